// Round 1
// 229.196 us; speedup vs baseline: 1.1278x; 1.1278x over previous
//
#include <hip/hip_runtime.h>
#include <hip/hip_bf16.h>

#define N_NODES 100000
#define N_PAD 100096         // 782 blocks * 128 rows
#define N_EDGES 600000
#define CH 128
#define N_GRAPHS 100
#define BN_EPS 1e-5f
#define NBUCKET 64
#define CAP 32               // per-node edge slab (max degree ~22 for Poisson(6))
#define OVFCAP 8192          // overflow safety list (never hit in practice)
#define FILL_BLOCKS 586      // ceil(N_EDGES / (256*4))
#define PRESCALE_BLOCKS 6250 // N_NODES*16/256

typedef __bf16 bf16x8 __attribute__((ext_vector_type(8)));
typedef float f32x4 __attribute__((ext_vector_type(4)));

__device__ __forceinline__ ushort f2bf(float f) {
    union { float f; unsigned u; } x; x.f = f;
    unsigned u = x.u;
    unsigned r = (u + 0x7fffu + ((u >> 16) & 1u)) >> 16;
    return (ushort)r;
}
__device__ __forceinline__ float bflo(unsigned p) { return __builtin_bit_cast(float, p << 16); }
__device__ __forceinline__ float bfhi(unsigned p) { return __builtin_bit_cast(float, p & 0xffff0000u); }

// ---------------------------------------------------------------------------
// k_front: one dispatch, three independent jobs:
//   [0, FILL)            : fused count+fill — slot = atomicAdd(&cnt[dst],1),
//                          esrc[dst*CAP+slot] = src (overflow -> ovf list)
//   [FILL, FILL+PRESC)   : xh = bf16(h*norm)
//   rest                 : Wt = bf16(W^T)
// This replaces the old hist -> scan -> fill chain (3 dispatches, 1.2M atomics)
// with a single 600K-atomic job overlapped with the streaming prescale.
// ---------------------------------------------------------------------------
__global__ __launch_bounds__(256) void k_front(const int* __restrict__ src,
        const int* __restrict__ dst, const float* __restrict__ h,
        const float* __restrict__ norm, const float* __restrict__ W,
        int* __restrict__ cnt, int* __restrict__ ovfcur, int* __restrict__ ovf,
        int* __restrict__ esrc, ushort* __restrict__ xh, ushort* __restrict__ Wt) {
    unsigned bid = blockIdx.x;
    if (bid < FILL_BLOCKS) {
        int e0 = (bid * 256 + threadIdx.x) * 4;
        if (e0 < N_EDGES) {                       // N_EDGES % 4 == 0 -> full int4 ok
            int4 d = *(const int4*)(dst + e0);
            int4 s = *(const int4*)(src + e0);
            int s0 = atomicAdd(&cnt[d.x], 1);
            int s1 = atomicAdd(&cnt[d.y], 1);
            int s2 = atomicAdd(&cnt[d.z], 1);
            int s3 = atomicAdd(&cnt[d.w], 1);
            if (s0 < CAP) esrc[d.x * CAP + s0] = s.x;
            else { int p = atomicAdd(ovfcur, 1); if (p < OVFCAP) { ovf[2*p] = d.x; ovf[2*p+1] = s.x; } }
            if (s1 < CAP) esrc[d.y * CAP + s1] = s.y;
            else { int p = atomicAdd(ovfcur, 1); if (p < OVFCAP) { ovf[2*p] = d.y; ovf[2*p+1] = s.y; } }
            if (s2 < CAP) esrc[d.z * CAP + s2] = s.z;
            else { int p = atomicAdd(ovfcur, 1); if (p < OVFCAP) { ovf[2*p] = d.z; ovf[2*p+1] = s.z; } }
            if (s3 < CAP) esrc[d.w * CAP + s3] = s.w;
            else { int p = atomicAdd(ovfcur, 1); if (p < OVFCAP) { ovf[2*p] = d.w; ovf[2*p+1] = s.w; } }
        }
    } else if (bid < FILL_BLOCKS + PRESCALE_BLOCKS) {
        int t = (bid - FILL_BLOCKS) * 256 + threadIdx.x;   // N_NODES*16
        int n = t >> 4, c = (t & 15) << 3;
        float nm = norm[n];
        float4 a = *(const float4*)(h + (size_t)n * CH + c);
        float4 d = *(const float4*)(h + (size_t)n * CH + c + 4);
        uint4 o;
        o.x = (unsigned)f2bf(a.x * nm) | ((unsigned)f2bf(a.y * nm) << 16);
        o.y = (unsigned)f2bf(a.z * nm) | ((unsigned)f2bf(a.w * nm) << 16);
        o.z = (unsigned)f2bf(d.x * nm) | ((unsigned)f2bf(d.y * nm) << 16);
        o.w = (unsigned)f2bf(d.z * nm) | ((unsigned)f2bf(d.w * nm) << 16);
        *(uint4*)(xh + (size_t)n * CH + c) = o;
    } else {
        int t = (bid - FILL_BLOCKS - PRESCALE_BLOCKS) * 256 + threadIdx.x;  // 16384
        int k = t >> 7, o = t & 127;
        Wt[o * CH + k] = f2bf(W[t]);
    }
}

// ---------------------------------------------------------------------------
// Gather: 16 lanes/node, 8 ch/lane (uint4 = 16B). Edge loop unrolled x4.
// Reads the fixed-stride slab esrc[n*CAP .. n*CAP+min(cnt,CAP)).
// Pad rows [N_NODES,N_PAD) get zeros (needed for GEMM A-frags).
// ---------------------------------------------------------------------------
__global__ __launch_bounds__(256) void k_gather(const ushort* __restrict__ xh,
        const float* __restrict__ norm, const int* __restrict__ cnt,
        const int* __restrict__ esrc, const int* __restrict__ ovfcur,
        const int* __restrict__ ovf, ushort* __restrict__ x2) {
    int t = blockIdx.x * 256 + threadIdx.x;
    int n = t >> 4;
    int c = (t & 15) << 3;                 // 8 channels
    if (n >= N_PAD) return;
    int e = 0;
    float nn = 0.f;
    if (n < N_NODES) { e = min(cnt[n], CAP); nn = norm[n]; }
    int base = n * CAP;
    float a0=0.f,a1=0.f,a2=0.f,a3=0.f,a4=0.f,a5=0.f,a6=0.f,a7=0.f;
    int j = 0;
    for (; j + 4 <= e; j += 4) {
        int s0 = esrc[base + j], s1 = esrc[base + j + 1];
        int s2 = esrc[base + j + 2], s3 = esrc[base + j + 3];
        uint4 v0 = *(const uint4*)(xh + (size_t)s0 * CH + c);
        uint4 v1 = *(const uint4*)(xh + (size_t)s1 * CH + c);
        uint4 v2 = *(const uint4*)(xh + (size_t)s2 * CH + c);
        uint4 v3 = *(const uint4*)(xh + (size_t)s3 * CH + c);
        a0 += bflo(v0.x) + bflo(v1.x) + bflo(v2.x) + bflo(v3.x);
        a1 += bfhi(v0.x) + bfhi(v1.x) + bfhi(v2.x) + bfhi(v3.x);
        a2 += bflo(v0.y) + bflo(v1.y) + bflo(v2.y) + bflo(v3.y);
        a3 += bfhi(v0.y) + bfhi(v1.y) + bfhi(v2.y) + bfhi(v3.y);
        a4 += bflo(v0.z) + bflo(v1.z) + bflo(v2.z) + bflo(v3.z);
        a5 += bfhi(v0.z) + bfhi(v1.z) + bfhi(v2.z) + bfhi(v3.z);
        a6 += bflo(v0.w) + bflo(v1.w) + bflo(v2.w) + bflo(v3.w);
        a7 += bfhi(v0.w) + bfhi(v1.w) + bfhi(v2.w) + bfhi(v3.w);
    }
    for (; j < e; j++) {
        int s = esrc[base + j];
        uint4 v = *(const uint4*)(xh + (size_t)s * CH + c);
        a0 += bflo(v.x); a1 += bfhi(v.x);
        a2 += bflo(v.y); a3 += bfhi(v.y);
        a4 += bflo(v.z); a5 += bfhi(v.z);
        a6 += bflo(v.w); a7 += bfhi(v.w);
    }
    // overflow edges (empty in practice; ovfcur broadcast-cached)
    if (n < N_NODES) {
        int no = *ovfcur;
        if (no > 0) {
            no = min(no, OVFCAP);
            for (int i = 0; i < no; i++) {
                if (ovf[2*i] == n) {
                    int s = ovf[2*i+1];
                    uint4 v = *(const uint4*)(xh + (size_t)s * CH + c);
                    a0 += bflo(v.x); a1 += bfhi(v.x);
                    a2 += bflo(v.y); a3 += bfhi(v.y);
                    a4 += bflo(v.z); a5 += bfhi(v.z);
                    a6 += bflo(v.w); a7 += bfhi(v.w);
                }
            }
        }
    }
    uint4 o;
    o.x = (unsigned)f2bf(a0 * nn) | ((unsigned)f2bf(a1 * nn) << 16);
    o.y = (unsigned)f2bf(a2 * nn) | ((unsigned)f2bf(a3 * nn) << 16);
    o.z = (unsigned)f2bf(a4 * nn) | ((unsigned)f2bf(a5 * nn) << 16);
    o.w = (unsigned)f2bf(a6 * nn) | ((unsigned)f2bf(a7 * nn) << 16);
    *(uint4*)(x2 + (size_t)n * CH + c) = o;
}

// ---------------------------------------------------------------------------
// GEMM: 128 rows/block, wave handles two 16-row tiles (B-frag register reuse).
// y16 = bf16(relu(x2@W + b)) via LDS-staged coalesced stores + BN stats.
// ---------------------------------------------------------------------------
__global__ __launch_bounds__(256) void k_gemm(const ushort* __restrict__ x2,
        const ushort* __restrict__ Wt, const float* __restrict__ bias,
        ushort* __restrict__ y16, float* __restrict__ psum, float* __restrict__ psq) {
    __shared__ ushort ys[128 * CH];   // 32 KB; reused as float[4096] for stats

    int tid = threadIdx.x;
    int w = tid >> 6, L = tid & 63;
    int c15 = L & 15, quad = L >> 4;
    size_t nb = (size_t)blockIdx.x * 128 + w * 32;   // wave's 32-row base

    const bf16x8* A0 = (const bf16x8*)(x2 + (nb + c15) * CH);
    const bf16x8* A1 = (const bf16x8*)(x2 + (nb + 16 + c15) * CH);

    f32x4 acc0[8] = {}, acc1[8] = {};
    #pragma unroll
    for (int kt = 0; kt < 4; kt++) {
        bf16x8 a0 = A0[kt * 4 + quad];
        bf16x8 a1 = A1[kt * 4 + quad];
        #pragma unroll
        for (int ot = 0; ot < 8; ot++) {
            bf16x8 b = *(const bf16x8*)(Wt + (size_t)(ot * 16 + c15) * CH + kt * 32 + quad * 8);
            acc0[ot] = __builtin_amdgcn_mfma_f32_16x16x32_bf16(a0, b, acc0[ot], 0, 0, 0);
            acc1[ot] = __builtin_amdgcn_mfma_f32_16x16x32_bf16(a1, b, acc1[ot], 0, 0, 0);
        }
    }

    float sA[8], qA[8];
    #pragma unroll
    for (int ot = 0; ot < 8; ot++) {
        int col = ot * 16 + c15;
        float bv = bias[col];
        float s_ = 0.f, q_ = 0.f;
        #pragma unroll
        for (int r = 0; r < 4; r++) {
            size_t n = nb + quad * 4 + r;
            float v = fmaxf(acc0[ot][r] + bv, 0.f);
            ys[(w * 32 + quad * 4 + r) * CH + col] = f2bf(v);
            if (n < N_NODES) { s_ += v; q_ += v * v; }
            size_t n2 = n + 16;
            float v2 = fmaxf(acc1[ot][r] + bv, 0.f);
            ys[(w * 32 + 16 + quad * 4 + r) * CH + col] = f2bf(v2);
            if (n2 < N_NODES) { s_ += v2; q_ += v2 * v2; }
        }
        sA[ot] = s_; qA[ot] = q_;
    }
    __syncthreads();

    // cooperative coalesced y16 store: 2048 uint4, 8 per thread
    {
        const uint4* ysv = (const uint4*)ys;
        uint4* out = (uint4*)(y16 + (size_t)blockIdx.x * 128 * CH);
        #pragma unroll
        for (int i = 0; i < 8; i++) out[tid + i * 256] = ysv[tid + i * 256];
    }
    __syncthreads();

    // stats reduction (reuse ys as float buffer: 2048 S + 2048 Q)
    float* red = (float*)ys;
    #pragma unroll
    for (int ot = 0; ot < 8; ot++) {
        red[ot * 256 + tid] = sA[ot];
        red[2048 + ot * 256 + tid] = qA[ot];
    }
    __syncthreads();

    if (tid < 128) {
        int ot = tid >> 4, cc = tid & 15;
        int col = ot * 16 + cc;
        float S = 0.f, Q = 0.f;
        #pragma unroll
        for (int g = 0; g < 16; g++) {
            int sl = (g >> 2) * 64 + (g & 3) * 16 + cc;
            S += red[ot * 256 + sl];
            Q += red[2048 + ot * 256 + sl];
        }
        int bucket = blockIdx.x & (NBUCKET - 1);
        atomicAdd(&psum[bucket * CH + col], S);
        atomicAdd(&psq[bucket * CH + col], Q);
    }
}

// ---------------------------------------------------------------------------
__global__ void k_finalize(const float* __restrict__ psum, const float* __restrict__ psq,
        const float* __restrict__ gamma, const float* __restrict__ beta,
        float* __restrict__ scale, float* __restrict__ shift, float* __restrict__ phis) {
    int t = threadIdx.x;   // 128
    float S = 0.f, Q = 0.f;
    for (int g = 0; g < NBUCKET; g++) { S += psum[g * CH + t]; Q += psq[g * CH + t]; }
    const float invN = 1.f / (float)N_NODES;
    float mean = S * invN;
    float var  = Q * invN - mean * mean;
    float sc   = gamma[t] * rsqrtf(var + BN_EPS);
    scale[t] = sc;
    shift[t] = beta[t] - mean * sc;
    for (int i = t; i < N_GRAPHS * CH; i += 128) phis[i] = 0.f;
}

// ---------------------------------------------------------------------------
// BN apply (bf16 y16 -> f32 x) + per-graph pooling.
// ---------------------------------------------------------------------------
__global__ __launch_bounds__(256) void k_bnpool(const ushort* __restrict__ y16,
        const int* __restrict__ gids, const float* __restrict__ scale,
        const float* __restrict__ shift, float* __restrict__ xout,
        float* __restrict__ phis) {
    __shared__ float smP[16][CH];   // 8 KB

    int tid = threadIdx.x;
    int cg = tid & 15, rl = tid >> 4;
    int c = cg * 8;
    int r0 = blockIdx.x * 256;
    int rbase = r0 + rl * 16;

    float4 sc0 = *(const float4*)(scale + c), sc1 = *(const float4*)(scale + c + 4);
    float4 sh0 = *(const float4*)(shift + c), sh1 = *(const float4*)(shift + c + 4);

    bool fast = (r0 + 255 < N_NODES) && (gids[r0] == gids[r0 + 255]);

    if (fast) {
        float4 p0 = make_float4(0.f,0.f,0.f,0.f), p1 = make_float4(0.f,0.f,0.f,0.f);
        for (int j = 0; j < 16; j++) {
            int r = rbase + j;
            uint4 v = *(const uint4*)(y16 + (size_t)r * CH + c);
            float4 f0, f1;
            f0.x = fmaf(bflo(v.x), sc0.x, sh0.x); f0.y = fmaf(bfhi(v.x), sc0.y, sh0.y);
            f0.z = fmaf(bflo(v.y), sc0.z, sh0.z); f0.w = fmaf(bfhi(v.y), sc0.w, sh0.w);
            f1.x = fmaf(bflo(v.z), sc1.x, sh1.x); f1.y = fmaf(bfhi(v.z), sc1.y, sh1.y);
            f1.z = fmaf(bflo(v.w), sc1.z, sh1.z); f1.w = fmaf(bfhi(v.w), sc1.w, sh1.w);
            *(float4*)(xout + (size_t)r * CH + c) = f0;
            *(float4*)(xout + (size_t)r * CH + c + 4) = f1;
            p0.x += f0.x; p0.y += f0.y; p0.z += f0.z; p0.w += f0.w;
            p1.x += f1.x; p1.y += f1.y; p1.z += f1.z; p1.w += f1.w;
        }
        *(float4*)&smP[rl][c] = p0;
        *(float4*)&smP[rl][c + 4] = p1;
        __syncthreads();
        if (tid < 128) {
            int g = gids[r0];
            float S = 0.f;
            #pragma unroll
            for (int k = 0; k < 16; k++) S += smP[k][tid];
            atomicAdd(&phis[(size_t)g * CH + tid], S);
        }
    } else {
        float p[8] = {};
        int gprev = -1;
        for (int j = 0; j < 16; j++) {
            int r = rbase + j;
            if (r >= N_NODES) break;
            int g = gids[r];
            if (g != gprev) {
                if (gprev >= 0) {
                    #pragma unroll
                    for (int k = 0; k < 8; k++) {
                        atomicAdd(&phis[(size_t)gprev * CH + c + k], p[k]);
                        p[k] = 0.f;
                    }
                }
                gprev = g;
            }
            uint4 v = *(const uint4*)(y16 + (size_t)r * CH + c);
            float f[8];
            f[0] = fmaf(bflo(v.x), sc0.x, sh0.x); f[1] = fmaf(bfhi(v.x), sc0.y, sh0.y);
            f[2] = fmaf(bflo(v.y), sc0.z, sh0.z); f[3] = fmaf(bfhi(v.y), sc0.w, sh0.w);
            f[4] = fmaf(bflo(v.z), sc1.x, sh1.x); f[5] = fmaf(bfhi(v.z), sc1.y, sh1.y);
            f[6] = fmaf(bflo(v.w), sc1.z, sh1.z); f[7] = fmaf(bfhi(v.w), sc1.w, sh1.w);
            *(float4*)(xout + (size_t)r * CH + c) = make_float4(f[0], f[1], f[2], f[3]);
            *(float4*)(xout + (size_t)r * CH + c + 4) = make_float4(f[4], f[5], f[6], f[7]);
            #pragma unroll
            for (int k = 0; k < 8; k++) p[k] += f[k];
        }
        if (gprev >= 0) {
            #pragma unroll
            for (int k = 0; k < 8; k++)
                atomicAdd(&phis[(size_t)gprev * CH + c + k], p[k]);
        }
    }
}

// ---------------------------------------------------------------------------
extern "C" void kernel_launch(void* const* d_in, const int* in_sizes, int n_in,
                              void* d_out, int out_size, void* d_ws, size_t ws_size,
                              hipStream_t stream)
{
    const float* h     = (const float*)d_in[0];
    const float* norm  = (const float*)d_in[1];
    const float* W     = (const float*)d_in[2];
    const float* b     = (const float*)d_in[3];
    const float* gamma = (const float*)d_in[4];
    const float* beta  = (const float*)d_in[5];
    const int*   src   = (const int*)d_in[6];
    const int*   dst   = (const int*)d_in[7];
    const int*   gids  = (const int*)d_in[8];

    float* x_out = (float*)d_out;                       // [N,128]
    float* phis  = x_out + (size_t)N_NODES * CH;        // [100,128]

    ushort* xh   = (ushort*)d_ws;                       // [N,128] bf16 h*norm
    ushort* x2   = xh + (size_t)N_NODES * CH;           // [N_PAD,128] bf16 agg
    ushort* y16  = x2 + (size_t)N_PAD * CH;             // [N_PAD,128] bf16 relu(xW+b)
    ushort* Wt   = y16 + (size_t)N_PAD * CH;            // [128,128] bf16 W^T
    // ---- zeroed region (single memset) ----
    int*   cnt     = (int*)(Wt + CH * CH);              // [N] per-node edge count/cursor
    float* psum    = (float*)(cnt + N_NODES);           // [64,128]
    float* psq     = psum + NBUCKET * CH;               // [64,128]
    int*   ovfcur  = (int*)(psq + NBUCKET * CH);        // [4] (padded for alignment)
    // ---- end zeroed region ----
    int*   esrc    = ovfcur + 4;                        // [N*CAP] strided slabs
    int*   ovf     = esrc + (size_t)N_NODES * CAP;      // [2*OVFCAP] (dst,src) pairs
    float* scale   = (float*)(ovf + 2 * OVFCAP);        // [128] (16B aligned)
    float* shift   = scale + CH;                        // [128]

    hipMemsetAsync(cnt, 0, (size_t)(N_NODES + 2 * NBUCKET * CH + 4) * sizeof(int), stream);

    k_front<<<FILL_BLOCKS + PRESCALE_BLOCKS + 64, 256, 0, stream>>>(
        src, dst, h, norm, W, cnt, ovfcur, ovf, esrc, xh, Wt);
    k_gather<<<N_PAD / 16, 256, 0, stream>>>(xh, norm, cnt, esrc, ovfcur, ovf, x2);
    k_gemm<<<N_PAD / 128, 256, 0, stream>>>(x2, Wt, b, y16, psum, psq);
    k_finalize<<<1, 128, 0, stream>>>(psum, psq, gamma, beta, scale, shift, phis);
    k_bnpool<<<(N_NODES + 255) / 256, 256, 0, stream>>>(y16, gids, scale, shift, x_out, phis);
}